// Round 8
// baseline (193.347 us; speedup 1.0000x reference)
//
#include <hip/hip_runtime.h>

#define N_NODES 100000
#define N_EDGES 1250000
#define FEATS 64

#define NPB   128                              // nodes per bucket (R0 proven)
#define NBUCK ((N_NODES + NPB - 1) / NPB)      // 782
#define CAP   2304                             // slots/bucket; mean 1600, sd 40 -> +17 sigma
#define TILE  4096
#define NTILES ((N_EDGES + TILE - 1) / TILE)   // 306
#define PK_BLOCKS ((N_NODES + 255) / 256)      // 391

typedef unsigned short ushort8 __attribute__((ext_vector_type(8)));

__device__ __forceinline__ float bf2f(unsigned short u) {
    return __uint_as_float(((unsigned int)u) << 16);
}
__device__ __forceinline__ unsigned short f2bf(float f) {
    unsigned int x = __float_as_uint(f);
    unsigned int lsb = (x >> 16) & 1u;
    x += 0x7fffu + lsb;                 // round-to-nearest-even
    return (unsigned short)(x >> 16);
}

// ---------------------------------------------------------------------------
// ws layout:
//   cursor [1024]            bucket sizes (memset 0; bin atomicAdd, relative)
//   pairs  int[782*2304]     packed (src<<7 | dst&127), 7.2 MB
//   hwb    ushort[6.4M]      bf16 (h @ W^T) copy, 12.8 MB
// ---------------------------------------------------------------------------

// NEW: aggregation is linear, so fold the 64x64 linear layer into the pack:
//   hw = h @ W^T  (fp32 compute, bf16 store).
// Thread-per-node, hr[64] fully static-indexed (stays in VGPRs), W rows are
// lane-uniform (scalar-load candidates, L2-hot 16 KB).
__global__ __launch_bounds__(256) void pack_kernel(
        const float* __restrict__ h,
        const float* __restrict__ W,    // [o][k] row-major
        unsigned short* __restrict__ hwb) {
    const int n = blockIdx.x * 256 + threadIdx.x;
    if (n >= N_NODES) return;

    float hr[FEATS];
    const float4* hp = (const float4*)(h + (size_t)n * FEATS);
#pragma unroll
    for (int k4 = 0; k4 < 16; ++k4) {
        float4 v = hp[k4];
        hr[k4 * 4 + 0] = v.x; hr[k4 * 4 + 1] = v.y;
        hr[k4 * 4 + 2] = v.z; hr[k4 * 4 + 3] = v.w;
    }

    for (int ob = 0; ob < 8; ++ob) {            // 8 output blocks of 8
        ushort8 u;
#pragma unroll
        for (int oi = 0; oi < 8; ++oi) {
            const float* wrow = W + (size_t)(ob * 8 + oi) * FEATS;
            float acc = 0.f;
#pragma unroll
            for (int k4 = 0; k4 < 16; ++k4) {
                float4 w = *(const float4*)(wrow + k4 * 4);  // lane-uniform
                acc = fmaf(hr[k4 * 4 + 0], w.x, acc);
                acc = fmaf(hr[k4 * 4 + 1], w.y, acc);
                acc = fmaf(hr[k4 * 4 + 2], w.z, acc);
                acc = fmaf(hr[k4 * 4 + 3], w.w, acc);
            }
            u[oi] = f2bf(acc);
        }
        *(ushort8*)(hwb + (size_t)n * FEATS + ob * 8) = u;
    }
}

// R0's binning, standalone (pack split out so this kernel's counters are
// finally attributable). 16 edges/thread, LDS hist, one global atomic per
// (tile,bucket), direct scatter.
__global__ __launch_bounds__(256) void bin_kernel(
        const int* __restrict__ src,
        const int* __restrict__ dst,
        int* __restrict__ cursor,
        int* __restrict__ pairs) {
    __shared__ int hist[NBUCK];
    __shared__ int base[NBUCK];
    const int t  = threadIdx.x;
    const int e0 = blockIdx.x * TILE + t * 16;
    const bool full = (blockIdx.x + 1) * TILE <= N_EDGES;

    for (int i = t; i < NBUCK; i += 256) hist[i] = 0;
    __syncthreads();

    int d[16], lr[16];
    if (full) {
#pragma unroll
        for (int q = 0; q < 4; ++q) {
            int4 v = *(const int4*)(dst + e0 + q * 4);
            d[q * 4 + 0] = v.x; d[q * 4 + 1] = v.y;
            d[q * 4 + 2] = v.z; d[q * 4 + 3] = v.w;
        }
#pragma unroll
        for (int j = 0; j < 16; ++j) lr[j] = atomicAdd(&hist[d[j] >> 7], 1);
    } else {
#pragma unroll
        for (int j = 0; j < 16; ++j) {
            if (e0 + j < N_EDGES) {
                d[j]  = dst[e0 + j];
                lr[j] = atomicAdd(&hist[d[j] >> 7], 1);
            }
        }
    }
    __syncthreads();

    for (int i = t; i < NBUCK; i += 256)
        base[i] = hist[i] ? atomicAdd(&cursor[i], hist[i]) : 0;   // relative
    __syncthreads();

    if (full) {
        int s[16];
#pragma unroll
        for (int q = 0; q < 4; ++q) {
            int4 v = *(const int4*)(src + e0 + q * 4);
            s[q * 4 + 0] = v.x; s[q * 4 + 1] = v.y;
            s[q * 4 + 2] = v.z; s[q * 4 + 3] = v.w;
        }
#pragma unroll
        for (int j = 0; j < 16; ++j) {
            int bk  = d[j] >> 7;
            int rel = base[bk] + lr[j];
            if (rel < CAP)                       // overflow guard (never hits)
                pairs[(size_t)bk * CAP + rel] = (s[j] << 7) | (d[j] & (NPB - 1));
        }
    } else {
#pragma unroll
        for (int j = 0; j < 16; ++j) {
            if (e0 + j < N_EDGES) {
                int bk  = d[j] >> 7;
                int rel = base[bk] + lr[j];
                if (rel < CAP)
                    pairs[(size_t)bk * CAP + rel] =
                        (src[e0 + j] << 7) | (d[j] & (NPB - 1));
            }
        }
    }
}

// ---------------------------------------------------------------------------
// R0's proven agg (counting sort + 8-lane-group register gather) minus the
// entire MLP epilogue (folded into pack_kernel). Epilogue is now just
// bias + relu + store. 256 threads, LDS 10.8 KB.
// ---------------------------------------------------------------------------
__global__ __launch_bounds__(256) void agg_kernel(
        const unsigned short* __restrict__ hwb,
        const int* __restrict__ pairs,
        const int* __restrict__ cursor,
        const float* __restrict__ bias,
        float* __restrict__ out) {
    __shared__ int ssrc[CAP];            // 9.2 KB sorted src ids
    __shared__ int lcnt[NPB];
    __shared__ int loff[NPB + 1];
    __shared__ int lcur[NPB];

    const int tid  = threadIdx.x;
    const int lane = tid & 63;
    const int wv   = tid >> 6;
    const int g    = lane >> 3;          // group 0..7
    const int li   = lane & 7;
    const int fo   = li * 8;             // my 8 feats

    const float4 bv0 = *(const float4*)(bias + fo);
    const float4 bv1 = *(const float4*)(bias + fo + 4);

    const int b = blockIdx.x;
    int size = cursor[b];
    if (size > CAP) size = CAP;
    const int* bp = pairs + (size_t)b * CAP;

    // -- counting sort by dst&127 (byte-identical to R0) --
    if (tid < NPB) lcnt[tid] = 0;
    __syncthreads();
    for (int i = tid; i < size; i += 256) atomicAdd(&lcnt[bp[i] & (NPB - 1)], 1);
    __syncthreads();
    if (tid < NPB) lcur[tid] = lcnt[tid];      // scan scratch
    __syncthreads();
    for (int off = 1; off < NPB; off <<= 1) {
        int y = 0;
        if (tid < NPB && tid >= off) y = lcur[tid - off];
        __syncthreads();
        if (tid < NPB) lcur[tid] += y;
        __syncthreads();
    }
    if (tid < NPB) loff[tid + 1] = lcur[tid];  // inclusive -> loff[1..128]
    if (tid == 0) loff[0] = 0;
    __syncthreads();
    if (tid < NPB) lcur[tid] = loff[tid];
    __syncthreads();
    for (int i = tid; i < size; i += 256) {
        int p = bp[i];
        int r = atomicAdd(&lcur[p & (NPB - 1)], 1);
        ssrc[r] = p >> 7;
    }
    __syncthreads();

    // -- gather (R0 inner loop) + bias/relu/store, 4 passes of 32 nodes --
#pragma unroll
    for (int pass = 0; pass < 4; ++pass) {
        const int ln  = pass * 32 + wv * 8 + g;
        const int beg = loff[ln];
        const int m   = loff[ln + 1] - beg;

        float acc0[8], acc1[8];
#pragma unroll
        for (int i = 0; i < 8; ++i) { acc0[i] = 0.f; acc1[i] = 0.f; }

        for (int base = 0; __any(base < m); base += 8) {
#pragma unroll
            for (int t = 0; t < 8; t += 2) {
                const int i0 = base + t, i1 = base + t + 1;
                int r0 = (i0 < m) ? ssrc[beg + i0] : 0;
                int r1 = (i1 < m) ? ssrc[beg + i1] : 0;
                if (i0 < m) {
                    ushort8 u = *(const ushort8*)(hwb + (size_t)r0 * FEATS + fo);
#pragma unroll
                    for (int i = 0; i < 8; ++i) acc0[i] += bf2f(u[i]);
                }
                if (i1 < m) {
                    ushort8 u = *(const ushort8*)(hwb + (size_t)r1 * FEATS + fo);
#pragma unroll
                    for (int i = 0; i < 8; ++i) acc1[i] += bf2f(u[i]);
                }
            }
        }

        const int nn = b * NPB + ln;
        if (nn < N_NODES) {
            float4 o0, o1;
            o0.x = fmaxf(acc0[0] + acc1[0] + bv0.x, 0.f);
            o0.y = fmaxf(acc0[1] + acc1[1] + bv0.y, 0.f);
            o0.z = fmaxf(acc0[2] + acc1[2] + bv0.z, 0.f);
            o0.w = fmaxf(acc0[3] + acc1[3] + bv0.w, 0.f);
            o1.x = fmaxf(acc0[4] + acc1[4] + bv1.x, 0.f);
            o1.y = fmaxf(acc0[5] + acc1[5] + bv1.y, 0.f);
            o1.z = fmaxf(acc0[6] + acc1[6] + bv1.z, 0.f);
            o1.w = fmaxf(acc0[7] + acc1[7] + bv1.w, 0.f);
            float* op = out + (size_t)nn * FEATS + fo;
            *(float4*)op       = o0;
            *(float4*)(op + 4) = o1;
        }
    }
}

extern "C" void kernel_launch(void* const* d_in, const int* in_sizes, int n_in,
                              void* d_out, int out_size, void* d_ws, size_t ws_size,
                              hipStream_t stream) {
    const float* h   = (const float*)d_in[0];
    const int*   src = (const int*)d_in[1];
    const int*   dst = (const int*)d_in[2];
    const float* W   = (const float*)d_in[3];
    const float* b   = (const float*)d_in[4];
    float* out = (float*)d_out;

    int* cursor = (int*)d_ws;                          // 1024 ints
    int* pairs  = cursor + 1024;                       // 782*2304 = 1.80M ints
    unsigned short* hwb = (unsigned short*)(pairs + (size_t)NBUCK * CAP);  // 12.8 MB

    hipMemsetAsync(cursor, 0, 1024 * sizeof(int), stream);
    bin_kernel<<<NTILES, 256, 0, stream>>>(src, dst, cursor, pairs);
    pack_kernel<<<PK_BLOCKS, 256, 0, stream>>>(h, W, hwb);
    agg_kernel<<<NBUCK, 256, 0, stream>>>(hwb, pairs, cursor, b, out);
}

// Round 9
// 192.713 us; speedup vs baseline: 1.0033x; 1.0033x over previous
//
#include <hip/hip_runtime.h>

#define N_NODES 100000
#define N_EDGES 1250000
#define FEATS 64

#define NPB   128                              // nodes per bucket (R0 proven)
#define NBUCK ((N_NODES + NPB - 1) / NPB)      // 782
#define CAP   2304                             // slots/bucket; mean 1600, sd 40 -> +17 sigma
#define TILE  4096
#define NTILES ((N_EDGES + TILE - 1) / TILE)   // 306
#define PK_NPB 64                              // nodes per pack block
#define PK_BLOCKS ((N_NODES + PK_NPB - 1) / PK_NPB)   // 1563

typedef unsigned short ushort8 __attribute__((ext_vector_type(8)));

__device__ __forceinline__ float bf2f(unsigned short u) {
    return __uint_as_float(((unsigned int)u) << 16);
}
__device__ __forceinline__ unsigned short f2bf(float f) {
    unsigned int x = __float_as_uint(f);
    unsigned int lsb = (x >> 16) & 1u;
    x += 0x7fffu + lsb;                 // round-to-nearest-even
    return (unsigned short)(x >> 16);
}

// ---------------------------------------------------------------------------
// ws layout:
//   cursor [1024]            bucket sizes (memset 0; bin atomicAdd, relative)
//   pairs  int[782*2304]     packed (src<<7 | dst&127), 7.2 MB
//   hwb    ushort[6.4M]      bf16 (h @ W^T) copy, 12.8 MB
// ---------------------------------------------------------------------------

// pack v2: hw = h @ W^T in R0's proven epilogue shape.
// R8's thread-per-node version was latency-starved (391 blocks, 6 waves/CU,
// VALUBusy 20%, 64 us). Now: 64-node tile per 256-thread block (1563 blocks,
// 24 waves/CU); h rows staged in LDS ([64][68] pad: 16B-aligned, rows
// spread across banks); lane = output feature; h read as wave-uniform b128
// broadcasts; W float4s remat-loaded from L1-hot global (R0 codegen, no
// wr[64] array -> no spill); unroll 2 shares each w4 across 2 nodes.
__global__ __launch_bounds__(256) void pack_kernel(
        const float* __restrict__ h,
        const float* __restrict__ W,    // [o][k] row-major
        unsigned short* __restrict__ hwb) {
    __shared__ float sh[PK_NPB][68];     // 17.4 KB

    const int tid  = threadIdx.x;
    const int lane = tid & 63;
    const int wv   = tid >> 6;
    const int n0   = blockIdx.x * PK_NPB;

    // stage 64 h rows, coalesced float4
#pragma unroll
    for (int it = 0; it < 4; ++it) {
        const int pos = it * 256 + tid;          // float4 index in tile
        const int row = pos >> 4;                // 16 float4 per row
        const int c4  = pos & 15;
        if (n0 + row < N_NODES) {
            float4 v = *(const float4*)(h + (size_t)(n0 + row) * FEATS + c4 * 4);
            *(float4*)&sh[row][c4 * 4] = v;
        }
    }
    __syncthreads();

    const float* wrow = W + (size_t)lane * FEATS;

    // each wave: 16 nodes; lane = output feature o
#pragma unroll 2
    for (int q = 0; q < 16; ++q) {
        const int nl = wv * 16 + q;
        const int nn = n0 + nl;
        if (nn >= N_NODES) break;
        const float4* ar = (const float4*)&sh[nl][0];
        float acc = 0.f;
#pragma unroll
        for (int k4 = 0; k4 < 16; ++k4) {
            float4 w4 = *(const float4*)(wrow + k4 * 4);  // L1-hot, remat
            float4 r  = ar[k4];                           // b128 broadcast
            acc = fmaf(r.x, w4.x, acc);
            acc = fmaf(r.y, w4.y, acc);
            acc = fmaf(r.z, w4.z, acc);
            acc = fmaf(r.w, w4.w, acc);
        }
        hwb[(size_t)nn * FEATS + lane] = f2bf(acc);       // 128 B/wave store
    }
}

// R0's binning, standalone (unchanged from R8). 16 edges/thread, LDS hist,
// one global atomic per (tile,bucket), direct scatter.
__global__ __launch_bounds__(256) void bin_kernel(
        const int* __restrict__ src,
        const int* __restrict__ dst,
        int* __restrict__ cursor,
        int* __restrict__ pairs) {
    __shared__ int hist[NBUCK];
    __shared__ int base[NBUCK];
    const int t  = threadIdx.x;
    const int e0 = blockIdx.x * TILE + t * 16;
    const bool full = (blockIdx.x + 1) * TILE <= N_EDGES;

    for (int i = t; i < NBUCK; i += 256) hist[i] = 0;
    __syncthreads();

    int d[16], lr[16];
    if (full) {
#pragma unroll
        for (int q = 0; q < 4; ++q) {
            int4 v = *(const int4*)(dst + e0 + q * 4);
            d[q * 4 + 0] = v.x; d[q * 4 + 1] = v.y;
            d[q * 4 + 2] = v.z; d[q * 4 + 3] = v.w;
        }
#pragma unroll
        for (int j = 0; j < 16; ++j) lr[j] = atomicAdd(&hist[d[j] >> 7], 1);
    } else {
#pragma unroll
        for (int j = 0; j < 16; ++j) {
            if (e0 + j < N_EDGES) {
                d[j]  = dst[e0 + j];
                lr[j] = atomicAdd(&hist[d[j] >> 7], 1);
            }
        }
    }
    __syncthreads();

    for (int i = t; i < NBUCK; i += 256)
        base[i] = hist[i] ? atomicAdd(&cursor[i], hist[i]) : 0;   // relative
    __syncthreads();

    if (full) {
        int s[16];
#pragma unroll
        for (int q = 0; q < 4; ++q) {
            int4 v = *(const int4*)(src + e0 + q * 4);
            s[q * 4 + 0] = v.x; s[q * 4 + 1] = v.y;
            s[q * 4 + 2] = v.z; s[q * 4 + 3] = v.w;
        }
#pragma unroll
        for (int j = 0; j < 16; ++j) {
            int bk  = d[j] >> 7;
            int rel = base[bk] + lr[j];
            if (rel < CAP)                       // overflow guard (never hits)
                pairs[(size_t)bk * CAP + rel] = (s[j] << 7) | (d[j] & (NPB - 1));
        }
    } else {
#pragma unroll
        for (int j = 0; j < 16; ++j) {
            if (e0 + j < N_EDGES) {
                int bk  = d[j] >> 7;
                int rel = base[bk] + lr[j];
                if (rel < CAP)
                    pairs[(size_t)bk * CAP + rel] =
                        (src[e0 + j] << 7) | (d[j] & (NPB - 1));
            }
        }
    }
}

// ---------------------------------------------------------------------------
// R0's proven agg (counting sort + 8-lane-group register gather), MLP folded
// out; epilogue = bias + relu + store. Unchanged from R8.
// ---------------------------------------------------------------------------
__global__ __launch_bounds__(256) void agg_kernel(
        const unsigned short* __restrict__ hwb,
        const int* __restrict__ pairs,
        const int* __restrict__ cursor,
        const float* __restrict__ bias,
        float* __restrict__ out) {
    __shared__ int ssrc[CAP];            // 9.2 KB sorted src ids
    __shared__ int lcnt[NPB];
    __shared__ int loff[NPB + 1];
    __shared__ int lcur[NPB];

    const int tid  = threadIdx.x;
    const int lane = tid & 63;
    const int wv   = tid >> 6;
    const int g    = lane >> 3;          // group 0..7
    const int li   = lane & 7;
    const int fo   = li * 8;             // my 8 feats

    const float4 bv0 = *(const float4*)(bias + fo);
    const float4 bv1 = *(const float4*)(bias + fo + 4);

    const int b = blockIdx.x;
    int size = cursor[b];
    if (size > CAP) size = CAP;
    const int* bp = pairs + (size_t)b * CAP;

    // -- counting sort by dst&127 (R0) --
    if (tid < NPB) lcnt[tid] = 0;
    __syncthreads();
    for (int i = tid; i < size; i += 256) atomicAdd(&lcnt[bp[i] & (NPB - 1)], 1);
    __syncthreads();
    if (tid < NPB) lcur[tid] = lcnt[tid];      // scan scratch
    __syncthreads();
    for (int off = 1; off < NPB; off <<= 1) {
        int y = 0;
        if (tid < NPB && tid >= off) y = lcur[tid - off];
        __syncthreads();
        if (tid < NPB) lcur[tid] += y;
        __syncthreads();
    }
    if (tid < NPB) loff[tid + 1] = lcur[tid];  // inclusive -> loff[1..128]
    if (tid == 0) loff[0] = 0;
    __syncthreads();
    if (tid < NPB) lcur[tid] = loff[tid];
    __syncthreads();
    for (int i = tid; i < size; i += 256) {
        int p = bp[i];
        int r = atomicAdd(&lcur[p & (NPB - 1)], 1);
        ssrc[r] = p >> 7;
    }
    __syncthreads();

    // -- gather (R0 inner loop) + bias/relu/store, 4 passes of 32 nodes --
#pragma unroll
    for (int pass = 0; pass < 4; ++pass) {
        const int ln  = pass * 32 + wv * 8 + g;
        const int beg = loff[ln];
        const int m   = loff[ln + 1] - beg;

        float acc0[8], acc1[8];
#pragma unroll
        for (int i = 0; i < 8; ++i) { acc0[i] = 0.f; acc1[i] = 0.f; }

        for (int base = 0; __any(base < m); base += 8) {
#pragma unroll
            for (int t = 0; t < 8; t += 2) {
                const int i0 = base + t, i1 = base + t + 1;
                int r0 = (i0 < m) ? ssrc[beg + i0] : 0;
                int r1 = (i1 < m) ? ssrc[beg + i1] : 0;
                if (i0 < m) {
                    ushort8 u = *(const ushort8*)(hwb + (size_t)r0 * FEATS + fo);
#pragma unroll
                    for (int i = 0; i < 8; ++i) acc0[i] += bf2f(u[i]);
                }
                if (i1 < m) {
                    ushort8 u = *(const ushort8*)(hwb + (size_t)r1 * FEATS + fo);
#pragma unroll
                    for (int i = 0; i < 8; ++i) acc1[i] += bf2f(u[i]);
                }
            }
        }

        const int nn = b * NPB + ln;
        if (nn < N_NODES) {
            float4 o0, o1;
            o0.x = fmaxf(acc0[0] + acc1[0] + bv0.x, 0.f);
            o0.y = fmaxf(acc0[1] + acc1[1] + bv0.y, 0.f);
            o0.z = fmaxf(acc0[2] + acc1[2] + bv0.z, 0.f);
            o0.w = fmaxf(acc0[3] + acc1[3] + bv0.w, 0.f);
            o1.x = fmaxf(acc0[4] + acc1[4] + bv1.x, 0.f);
            o1.y = fmaxf(acc0[5] + acc1[5] + bv1.y, 0.f);
            o1.z = fmaxf(acc0[6] + acc1[6] + bv1.z, 0.f);
            o1.w = fmaxf(acc0[7] + acc1[7] + bv1.w, 0.f);
            float* op = out + (size_t)nn * FEATS + fo;
            *(float4*)op       = o0;
            *(float4*)(op + 4) = o1;
        }
    }
}

extern "C" void kernel_launch(void* const* d_in, const int* in_sizes, int n_in,
                              void* d_out, int out_size, void* d_ws, size_t ws_size,
                              hipStream_t stream) {
    const float* h   = (const float*)d_in[0];
    const int*   src = (const int*)d_in[1];
    const int*   dst = (const int*)d_in[2];
    const float* W   = (const float*)d_in[3];
    const float* b   = (const float*)d_in[4];
    float* out = (float*)d_out;

    int* cursor = (int*)d_ws;                          // 1024 ints
    int* pairs  = cursor + 1024;                       // 782*2304 = 1.80M ints
    unsigned short* hwb = (unsigned short*)(pairs + (size_t)NBUCK * CAP);  // 12.8 MB

    hipMemsetAsync(cursor, 0, 1024 * sizeof(int), stream);
    bin_kernel<<<NTILES, 256, 0, stream>>>(src, dst, cursor, pairs);
    pack_kernel<<<PK_BLOCKS, 256, 0, stream>>>(h, W, hwb);
    agg_kernel<<<NBUCK, 256, 0, stream>>>(hwb, pairs, cursor, b, out);
}